// Round 8
// baseline (111.537 us; speedup 1.0000x reference)
//
#include <hip/hip_runtime.h>
#include <math.h>

// MatchNet: MLP(6->20->20->20->8, tanh) then 150-iter PDHG LP per row.
// One thread per batch row; all PDHG state in scalars.
//
// MODEL (R1-R6): wall = issue-slots/wave x ~0.376us/slot (per 150 it),
// schedule/dependency/VGPR-invariant; only lever is slots/wave.
// N_ITERS must stay 150 (R6: iterate moves ~0.5 between it 100 and 150).
//
// R7 post-mortem: S-dual shift dropped a PER-ITERATION -cb (only constant
// shifts are absorbable) -> dual drift, absmax 0.71. R8 fixes: YS stays
// UNSHIFTED (fma + sub + max, as R4); the TI fold is kept because there
// the subtracted term IS the constant shift: TI := (tau - z) + YI,
//   TI = max(t, fma(-c, xb, TI)),  d = (x + TI) - colsum(YS)   [exact]
// Slots/iter: 6+6+18+16+9+8+8+8+3+8+8 = 98 (R4: 110).
// scale = max(0, 1 - tauC*rsq(nsq)); rsq(0)=inf -> scale=0 == ref clamp.

#define N_ITERS 150

__device__ __forceinline__ float fast_tanh(float a) {
    float e = __expf(2.0f * a);
    return 1.0f - 2.0f * __builtin_amdgcn_rcpf(e + 1.0f);
}

__global__ void __launch_bounds__(64)
__attribute__((amdgpu_waves_per_eu(1, 1)))
matchnet_kernel(
    const float* __restrict__ X,
    const float* __restrict__ W1, const float* __restrict__ b1,
    const float* __restrict__ W2, const float* __restrict__ b2,
    const float* __restrict__ W3, const float* __restrict__ b3,
    const float* __restrict__ W4, const float* __restrict__ b4,
    float* __restrict__ out, int B)
{
    __shared__ float sW1[120], sW2[400], sW3[400], sW4[160];
    __shared__ float sb1[20], sb2[20], sb3[20], sb4[8];
    for (int i = threadIdx.x; i < 120; i += blockDim.x) sW1[i] = W1[i];
    for (int i = threadIdx.x; i < 400; i += blockDim.x) sW2[i] = W2[i];
    for (int i = threadIdx.x; i < 400; i += blockDim.x) sW3[i] = W3[i];
    for (int i = threadIdx.x; i < 160; i += blockDim.x) sW4[i] = W4[i];
    if (threadIdx.x < 20) {
        sb1[threadIdx.x] = b1[threadIdx.x];
        sb2[threadIdx.x] = b2[threadIdx.x];
        sb3[threadIdx.x] = b3[threadIdx.x];
    }
    if (threadIdx.x < 8) sb4[threadIdx.x] = b4[threadIdx.x];
    __syncthreads();

    int row = blockIdx.x * blockDim.x + threadIdx.x;
    if (row >= B) return;

    float bb0 = X[row * 6 + 0], bb1 = X[row * 6 + 1], bb2 = X[row * 6 + 2];
    float bb3 = X[row * 6 + 3], bb4 = X[row * 6 + 4], bb5 = X[row * 6 + 5];

    // --- MLP ---
    float h1[20], h2[20];
    #pragma unroll
    for (int j = 0; j < 20; j++) {
        float acc = sb1[j];
        acc = fmaf(bb0, sW1[0 * 20 + j], acc);
        acc = fmaf(bb1, sW1[1 * 20 + j], acc);
        acc = fmaf(bb2, sW1[2 * 20 + j], acc);
        acc = fmaf(bb3, sW1[3 * 20 + j], acc);
        acc = fmaf(bb4, sW1[4 * 20 + j], acc);
        acc = fmaf(bb5, sW1[5 * 20 + j], acc);
        h1[j] = fast_tanh(acc);
    }
    #pragma unroll
    for (int j = 0; j < 20; j++) {
        float acc = sb2[j];
        #pragma unroll
        for (int i = 0; i < 20; i++) acc = fmaf(h1[i], sW2[i * 20 + j], acc);
        h2[j] = fast_tanh(acc);
    }
    #pragma unroll
    for (int j = 0; j < 20; j++) {
        float acc = sb3[j];
        #pragma unroll
        for (int i = 0; i < 20; i++) acc = fmaf(h2[i], sW3[i * 20 + j], acc);
        h1[j] = fast_tanh(acc);   // reuse h1 as h3
    }
    float z0, z1, z2, z3, z4, z5, z6, z7;
    {
        float zt[8];
        #pragma unroll
        for (int k = 0; k < 8; k++) {
            float acc = sb4[k];
            #pragma unroll
            for (int i = 0; i < 20; i++) acc = fmaf(h1[i], sW4[i * 8 + k], acc);
            zt[k] = acc;
        }
        z0 = zt[0]; z1 = zt[1]; z2 = zt[2]; z3 = zt[3];
        z4 = zt[4]; z5 = zt[5]; z6 = zt[6]; z7 = zt[7];
    }

    // --- PDHG constants / invariants ---
    const float tau  = 0.18898223650461363f;   // 1/sqrt(28)
    const float c    = 0.03571428571428571f;   // tau*sigma = 1/28
    const float tauC = 1.8898223650461363f;    // tau * control_strength(10)

    float cb0 = c * bb0, cb1 = c * bb1, cb2 = c * bb2;
    float cb3 = c * bb3, cb4 = c * bb4, cb5 = c * bb5;

    // t_k = tau - z_k ; TI := t + YI, init TI = t (YI=0). Exact shift:
    // TI_new = t + max(0, (TI-t) - c*xb) = max(t, TI - c*xb).
    float t0 = tau - z0, t1 = tau - z1, t2 = tau - z2, t3 = tau - z3;
    float t4 = tau - z4, t5 = tau - z5, t6 = tau - z6, t7 = tau - z7;
    float TI0 = t0, TI1 = t1, TI2 = t2, TI3 = t3;
    float TI4 = t4, TI5 = t5, TI6 = t6, TI7 = t7;

    float x0 = fmaxf(z0, 0.0f), x1 = fmaxf(z1, 0.0f), x2 = fmaxf(z2, 0.0f), x3 = fmaxf(z3, 0.0f);
    float x4 = fmaxf(z4, 0.0f), x5 = fmaxf(z5, 0.0f), x6 = fmaxf(z6, 0.0f), x7 = fmaxf(z7, 0.0f);
    float xb0 = x0, xb1 = x1, xb2 = x2, xb3 = x3, xb4 = x4, xb5 = x5, xb6 = x6, xb7 = x7;
    // S-duals (scaled by tau, UNSHIFTED): YS_j = tau*y_j, init 0
    float Y0 = 0.f, Y1 = 0.f, Y2 = 0.f, Y3 = 0.f, Y4 = 0.f, Y5 = 0.f;

    #pragma unroll 1
    for (int it = 0; it < N_ITERS; it++) {
        // s partials (6) + sums (6)
        float t07 = xb0 + xb7, t25 = xb2 + xb5, t12 = xb1 + xb2;
        float t47 = xb4 + xb7, t34 = xb3 + xb4, t06 = xb0 + xb6;
        float s0 = t07 + t25, s1 = t34 + xb1, s2 = t06 + xb1;
        float s3 = t25 + xb3, s4 = t12 + t47, s5 = t06 + xb4;

        // S-dual update (18): Y = max(0, fma(c, s, Y) - cb)
        Y0 = fmaxf(0.f, fmaf(c, s0, Y0) - cb0);
        Y1 = fmaxf(0.f, fmaf(c, s1, Y1) - cb1);
        Y2 = fmaxf(0.f, fmaf(c, s2, Y2) - cb2);
        Y3 = fmaxf(0.f, fmaf(c, s3, Y3) - cb3);
        Y4 = fmaxf(0.f, fmaf(c, s4, Y4) - cb4);
        Y5 = fmaxf(0.f, fmaf(c, s5, Y5) - cb5);

        // I-dual (folded, 16): TI = max(t, fma(-c, xb, TI))
        TI0 = fmaxf(t0, fmaf(-c, xb0, TI0));
        TI1 = fmaxf(t1, fmaf(-c, xb1, TI1));
        TI2 = fmaxf(t2, fmaf(-c, xb2, TI2));
        TI3 = fmaxf(t3, fmaf(-c, xb3, TI3));
        TI4 = fmaxf(t4, fmaf(-c, xb4, TI4));
        TI5 = fmaxf(t5, fmaf(-c, xb5, TI5));
        TI6 = fmaxf(t6, fmaf(-c, xb6, TI6));
        TI7 = fmaxf(t7, fmaf(-c, xb7, TI7));

        // column sums (9); col5 = r03, col6 = r25
        float r03 = Y0 + Y3, r25 = Y2 + Y5, r14 = Y1 + Y4;
        float c0 = r25 + Y0, c1 = r14 + Y2, c2 = r03 + Y4;
        float c3 = Y1 + Y3,  c4 = r14 + Y5, c7 = Y0 + Y4;

        // d = (x + TI) - col  (16)
        float dA0 = x0 + TI0, dA1 = x1 + TI1, dA2 = x2 + TI2, dA3 = x3 + TI3;
        float dA4 = x4 + TI4, dA5 = x5 + TI5, dA6 = x6 + TI6, dA7 = x7 + TI7;
        float d0 = dA0 - c0, d1 = dA1 - c1, d2 = dA2 - c2, d3 = dA3 - c3;
        float d4 = dA4 - c4, d5 = dA5 - r03, d6 = dA6 - r25, d7 = dA7 - c7;

        // ||d||^2 serial fma chain (8)
        float nsq = d0 * d0;
        nsq = fmaf(d1, d1, nsq);
        nsq = fmaf(d2, d2, nsq);
        nsq = fmaf(d3, d3, nsq);
        nsq = fmaf(d4, d4, nsq);
        nsq = fmaf(d5, d5, nsq);
        nsq = fmaf(d6, d6, nsq);
        nsq = fmaf(d7, d7, nsq);

        // scale (3)
        float rs = __builtin_amdgcn_rsqf(nsq);
        float scale = fmaxf(0.0f, fmaf(-tauC, rs, 1.0f));

        // xn (8), xb commit (8)
        float xn0 = fmaf(scale, d0, z0), xn1 = fmaf(scale, d1, z1);
        float xn2 = fmaf(scale, d2, z2), xn3 = fmaf(scale, d3, z3);
        float xn4 = fmaf(scale, d4, z4), xn5 = fmaf(scale, d5, z5);
        float xn6 = fmaf(scale, d6, z6), xn7 = fmaf(scale, d7, z7);
        xb0 = fmaf(2.0f, xn0, -x0); x0 = xn0;
        xb1 = fmaf(2.0f, xn1, -x1); x1 = xn1;
        xb2 = fmaf(2.0f, xn2, -x2); x2 = xn2;
        xb3 = fmaf(2.0f, xn3, -x3); x3 = xn3;
        xb4 = fmaf(2.0f, xn4, -x4); x4 = xn4;
        xb5 = fmaf(2.0f, xn5, -x5); x5 = xn5;
        xb6 = fmaf(2.0f, xn6, -x6); x6 = xn6;
        xb7 = fmaf(2.0f, xn7, -x7); x7 = xn7;
    }

    float4* out4 = (float4*)out;
    out4[row * 2 + 0] = make_float4(x0, x1, x2, x3);
    out4[row * 2 + 1] = make_float4(x4, x5, x6, x7);
}

extern "C" void kernel_launch(void* const* d_in, const int* in_sizes, int n_in,
                              void* d_out, int out_size, void* d_ws, size_t ws_size,
                              hipStream_t stream) {
    const float* X  = (const float*)d_in[0];
    const float* W1 = (const float*)d_in[1];
    const float* b1 = (const float*)d_in[2];
    const float* W2 = (const float*)d_in[3];
    const float* b2 = (const float*)d_in[4];
    const float* W3 = (const float*)d_in[5];
    const float* b3 = (const float*)d_in[6];
    const float* W4 = (const float*)d_in[7];
    const float* b4 = (const float*)d_in[8];
    float* out = (float*)d_out;

    int B = in_sizes[0] / 6;
    const int block = 64;
    int grid = (B + block - 1) / block;
    hipLaunchKernelGGL(matchnet_kernel, dim3(grid), dim3(block), 0, stream,
                       X, W1, b1, W2, b2, W3, b3, W4, b4, out, B);
}

// Round 9
// 104.585 us; speedup vs baseline: 1.0665x; 1.0665x over previous
//
#include <hip/hip_runtime.h>
#include <math.h>

// MatchNet: MLP(6->20->20->20->8, tanh) then 150-iter PDHG LP per row.
// R9: TWO LANES PER ROW (even lane owns components 0-3, odd owns 4-7).
// State is LANE-RELATIVE; DPP quad_perm[1,0,3,2] swaps even<->odd so each
// lane sees the partner's values with swapped register roles. Dual rows
// split E={0,2,1}, O={4,3,5}; the op patterns below are chosen so one SIMT
// instruction computes a different-but-correct value per lane parity
// (verified by hand against S):
//   op_a=oxb0+rxb1: even xb0+xb5 (s0-part), odd xb4+xb1 (s4-part)
//   op_m=Yq0+rY0:   even Y0+Y4 (col2-part), odd Y4+Y0 (= col7 complete)
//   op_n=rY1+Yq2:   even Y3+Y1 (= col3),    odd Y2+Y5 (= col6)
// Loop = 72 issue slots vs R8's 98. Exact f32 (absmax must stay ~0.00195).
// MLP kept lane-redundant (both lanes compute the row's full MLP).
// N_ITERS must stay 150 (R6: trajectory still moves ~0.5 between 100..150).

#define N_ITERS 150

__device__ __forceinline__ float fast_tanh(float a) {
    float e = __expf(2.0f * a);
    return 1.0f - 2.0f * __builtin_amdgcn_rcpf(e + 1.0f);
}

__device__ __forceinline__ float dpp_swap(float v) {
    // quad_perm [1,0,3,2]: lane pairs (2k,2k+1) exchange
    union { float f; int i; } u;
    u.f = v;
    u.i = __builtin_amdgcn_update_dpp(0, u.i, 0xB1, 0xF, 0xF, true);
    return u.f;
}

__global__ void __launch_bounds__(64)
__attribute__((amdgpu_waves_per_eu(1, 1)))
matchnet_kernel(
    const float* __restrict__ X,
    const float* __restrict__ W1, const float* __restrict__ b1,
    const float* __restrict__ W2, const float* __restrict__ b2,
    const float* __restrict__ W3, const float* __restrict__ b3,
    const float* __restrict__ W4, const float* __restrict__ b4,
    float* __restrict__ out, int B)
{
    __shared__ float sW1[120], sW2[400], sW3[400], sW4[160];
    __shared__ float sb1[20], sb2[20], sb3[20], sb4[8];
    for (int i = threadIdx.x; i < 120; i += blockDim.x) sW1[i] = W1[i];
    for (int i = threadIdx.x; i < 400; i += blockDim.x) sW2[i] = W2[i];
    for (int i = threadIdx.x; i < 400; i += blockDim.x) sW3[i] = W3[i];
    for (int i = threadIdx.x; i < 160; i += blockDim.x) sW4[i] = W4[i];
    if (threadIdx.x < 20) {
        sb1[threadIdx.x] = b1[threadIdx.x];
        sb2[threadIdx.x] = b2[threadIdx.x];
        sb3[threadIdx.x] = b3[threadIdx.x];
    }
    if (threadIdx.x < 8) sb4[threadIdx.x] = b4[threadIdx.x];
    __syncthreads();

    int gidx = blockIdx.x * blockDim.x + threadIdx.x;
    int row = gidx >> 1;
    if (row >= B) return;
    const bool isOdd = (gidx & 1) != 0;

    float bb0 = X[row * 6 + 0], bb1 = X[row * 6 + 1], bb2 = X[row * 6 + 2];
    float bb3 = X[row * 6 + 3], bb4 = X[row * 6 + 4], bb5 = X[row * 6 + 5];

    // --- MLP (lane-redundant: both lanes of a pair compute the full row) ---
    float h1[20], h2[20];
    #pragma unroll
    for (int j = 0; j < 20; j++) {
        float acc = sb1[j];
        acc = fmaf(bb0, sW1[0 * 20 + j], acc);
        acc = fmaf(bb1, sW1[1 * 20 + j], acc);
        acc = fmaf(bb2, sW1[2 * 20 + j], acc);
        acc = fmaf(bb3, sW1[3 * 20 + j], acc);
        acc = fmaf(bb4, sW1[4 * 20 + j], acc);
        acc = fmaf(bb5, sW1[5 * 20 + j], acc);
        h1[j] = fast_tanh(acc);
    }
    #pragma unroll
    for (int j = 0; j < 20; j++) {
        float acc = sb2[j];
        #pragma unroll
        for (int i = 0; i < 20; i++) acc = fmaf(h1[i], sW2[i * 20 + j], acc);
        h2[j] = fast_tanh(acc);
    }
    #pragma unroll
    for (int j = 0; j < 20; j++) {
        float acc = sb3[j];
        #pragma unroll
        for (int i = 0; i < 20; i++) acc = fmaf(h2[i], sW3[i * 20 + j], acc);
        h1[j] = fast_tanh(acc);   // reuse h1 as h3
    }
    float z[8];
    #pragma unroll
    for (int k = 0; k < 8; k++) {
        float acc = sb4[k];
        #pragma unroll
        for (int i = 0; i < 20; i++) acc = fmaf(h1[i], sW4[i * 8 + k], acc);
        z[k] = acc;
    }

    // --- constants ---
    const float tau  = 0.18898223650461363f;   // 1/sqrt(28)
    const float c    = 0.03571428571428571f;   // tau*sigma = 1/28
    const float tauC = 1.8898223650461363f;    // tau * control_strength(10)

    // --- parity collapse: this lane's 4 components ---
    float oz0 = isOdd ? z[4] : z[0];
    float oz1 = isOdd ? z[5] : z[1];
    float oz2 = isOdd ? z[6] : z[2];
    float oz3 = isOdd ? z[7] : z[3];

    float ot0 = tau - oz0, ot1 = tau - oz1, ot2 = tau - oz2, ot3 = tau - oz3;
    float oTI0 = ot0, oTI1 = ot1, oTI2 = ot2, oTI3 = ot3;

    float ox0 = fmaxf(oz0, 0.f), ox1 = fmaxf(oz1, 0.f);
    float ox2 = fmaxf(oz2, 0.f), ox3 = fmaxf(oz3, 0.f);
    float oxb0 = ox0, oxb1 = ox1, oxb2 = ox2, oxb3 = ox3;

    // dual-row constants: even rows (0,2,1) -> (cb0,cb2,cb1); odd (4,3,5)
    float cb0 = c * bb0, cb1 = c * bb1, cb2 = c * bb2;
    float cb3 = c * bb3, cb4 = c * bb4, cb5 = c * bb5;
    float cbq0 = isOdd ? cb4 : cb0;
    float cbq1 = isOdd ? cb3 : cb2;
    float cbq2 = isOdd ? cb5 : cb1;
    float Yq0 = 0.f, Yq1 = 0.f, Yq2 = 0.f;

    #pragma unroll 1
    for (int it = 0; it < N_ITERS; it++) {
        // xb exchange (4): rxb_i = partner's oxb_i
        float rxb0 = dpp_swap(oxb0), rxb1 = dpp_swap(oxb1);
        float rxb2 = dpp_swap(oxb2), rxb3 = dpp_swap(oxb3);

        // s-sums (12): even (s0,s2,s1), odd (s4,s3,s5)
        float op_a = oxb0 + rxb1;            // e: xb0+xb5 | o: xb4+xb1
        float op_b = oxb2 + rxb3;            // e: xb2+xb7 | o: garbage
        float op_c = oxb3 + rxb2;            // e: garbage | o: xb7+xb2
        float op_d = isOdd ? op_c : op_b;
        float sq0  = op_a + op_d;            // e: s0 | o: s4
        float op_e = oxb1 + rxb2;            // e: xb1+xb6 | o: xb5+xb2
        float op_f = isOdd ? rxb3 : oxb0;    // e: xb0 | o: xb3
        float sq1  = op_e + op_f;            // e: s2 | o: s3
        float op_g = oxb1 + oxb3;            // e: xb1+xb3
        float op_h = oxb0 + oxb2;            //            o: xb4+xb6
        float op_i = isOdd ? op_h : op_g;
        float sq2  = op_i + rxb0;            // e: s1 | o: s5

        // Y updates (9): Y = max(0, fma(c,s,Y) - cb)
        Yq0 = fmaxf(0.f, fmaf(c, sq0, Yq0) - cbq0);
        Yq1 = fmaxf(0.f, fmaf(c, sq1, Yq1) - cbq1);
        Yq2 = fmaxf(0.f, fmaf(c, sq2, Yq2) - cbq2);

        // Y exchange (3): e gets (Y4,Y3,Y5); o gets (Y0,Y2,Y1)
        float rY0 = dpp_swap(Yq0), rY1 = dpp_swap(Yq1), rY2 = dpp_swap(Yq2);

        // column sums (11): even cols 0-3, odd cols 4-7
        float op_j = Yq0 + rY2;              // e: Y0+Y5 | o: Y4+Y5
        float op_k = isOdd ? Yq2 : Yq1;      // e: Y2    | o: Y5? no: Yq2 odd=Y5? wait
        // even colq0 = Y0+Y5+Y2 = col0 ; odd colq0 = Y4+Y1+Y5 = col4
        // odd op_j = Yq0+rY2 = Y4+Y1 ; odd op_k = Yq2 = Y5  -> col4 OK
        // even op_j = Y0+Y5   ; even op_k = Yq1 = Y2        -> col0 OK
        float colq0 = op_j + op_k;
        float op_l = Yq1 + rY0;              // e: Y2+Y4 | o: Y3+Y0
        float op_p = isOdd ? 0.f : Yq2;      // e: Y1    | o: 0
        float colq1 = op_l + op_p;           // e: col1  | o: col5
        float op_m = Yq0 + rY0;              // e: Y0+Y4 | o: Y4+Y0 (=col7)
        float op_n = rY1 + Yq2;              // e: Y3+Y1 (=col3) | o: Y2+Y5 (=col6)
        float op_o = op_m + rY1;             // e: Y0+Y4+Y3 (=col2) | o: garbage
        float colq2 = isOdd ? op_n : op_o;   // e: col2 | o: col6
        float colq3 = isOdd ? op_m : op_n;   // e: col3 | o: col7

        // TI (8): TI = max(t, fma(-c, xb, TI))
        oTI0 = fmaxf(ot0, fmaf(-c, oxb0, oTI0));
        oTI1 = fmaxf(ot1, fmaf(-c, oxb1, oTI1));
        oTI2 = fmaxf(ot2, fmaf(-c, oxb2, oTI2));
        oTI3 = fmaxf(ot3, fmaf(-c, oxb3, oTI3));

        // d = (x + TI) - col  (8)
        float od0 = (ox0 + oTI0) - colq0;
        float od1 = (ox1 + oTI1) - colq1;
        float od2 = (ox2 + oTI2) - colq2;
        float od3 = (ox3 + oTI3) - colq3;

        // nsq (6): local 4-term + cross-lane add (commutative => identical)
        float nl = od0 * od0;
        nl = fmaf(od1, od1, nl);
        nl = fmaf(od2, od2, nl);
        nl = fmaf(od3, od3, nl);
        float rn = dpp_swap(nl);
        float nsq = nl + rn;

        // scale (3): max(0, 1 - tauC*rsq(nsq)); rsq(0)=inf -> 0 == ref clamp
        float rs = __builtin_amdgcn_rsqf(nsq);
        float scale = fmaxf(0.f, fmaf(-tauC, rs, 1.f));

        // xn + xb commit (8)
        float xn0 = fmaf(scale, od0, oz0);
        float xn1 = fmaf(scale, od1, oz1);
        float xn2 = fmaf(scale, od2, oz2);
        float xn3 = fmaf(scale, od3, oz3);
        oxb0 = fmaf(2.f, xn0, -ox0); ox0 = xn0;
        oxb1 = fmaf(2.f, xn1, -ox1); ox1 = xn1;
        oxb2 = fmaf(2.f, xn2, -ox2); ox2 = xn2;
        oxb3 = fmaf(2.f, xn3, -ox3); ox3 = xn3;
    }

    // even lane: comps 0-3 at out4[row*2]; odd: comps 4-7 at out4[row*2+1]
    float4* out4 = (float4*)out;
    out4[gidx] = make_float4(ox0, ox1, ox2, ox3);
}

extern "C" void kernel_launch(void* const* d_in, const int* in_sizes, int n_in,
                              void* d_out, int out_size, void* d_ws, size_t ws_size,
                              hipStream_t stream) {
    const float* X  = (const float*)d_in[0];
    const float* W1 = (const float*)d_in[1];
    const float* b1 = (const float*)d_in[2];
    const float* W2 = (const float*)d_in[3];
    const float* b2 = (const float*)d_in[4];
    const float* W3 = (const float*)d_in[5];
    const float* b3 = (const float*)d_in[6];
    const float* W4 = (const float*)d_in[7];
    const float* b4 = (const float*)d_in[8];
    float* out = (float*)d_out;

    int B = in_sizes[0] / 6;
    const int block = 64;
    long long threads = (long long)B * 2;
    int grid = (int)((threads + block - 1) / block);
    hipLaunchKernelGGL(matchnet_kernel, dim3(grid), dim3(block), 0, stream,
                       X, W1, b1, W2, b2, W3, b3, W4, b4, out, B);
}

// Round 10
// 101.679 us; speedup vs baseline: 1.0970x; 1.0286x over previous
//
#include <hip/hip_runtime.h>
#include <math.h>

// MatchNet: MLP(6->20->20->20->8, tanh) then 150-iter PDHG LP per row.
// R9 (verified, absmax bit-exact 0.001953125): TWO LANES PER ROW, PDHG
// state lane-relative, DPP quad_perm[1,0,3,2] pair exchange, 72 slots/iter.
// R10: loop kept BYTE-IDENTICAL; MLP split across the lane pair:
//  - each lane computes 10 neurons/layer (even j0-9, odd j10-19)
//  - weights staged TRANSPOSED in LDS -> per-neuron contiguous vector reads
//  - after each layer: 10 dpp + 20 cndmask reassemble h in ABSOLUTE order
//    so every fma accumulates in the reference's i-ascending order (bit-exact)
//  - L4 outputs split 4/4 == exactly the z components each lane owns
// MLP slots ~2700 -> ~950 (cadence model: wall ~ slots/wave x 2.8ns).
// N_ITERS must stay 150 (R6: trajectory moves ~0.5 between it 100 and 150).

#define N_ITERS 150
typedef float f2 __attribute__((ext_vector_type(2)));
typedef float f4 __attribute__((ext_vector_type(4)));

__device__ __forceinline__ float fast_tanh(float a) {
    float e = __expf(2.0f * a);
    return 1.0f - 2.0f * __builtin_amdgcn_rcpf(e + 1.0f);
}

__device__ __forceinline__ float dpp_swap(float v) {
    // quad_perm [1,0,3,2]: lane pairs (2k,2k+1) exchange
    union { float f; int i; } u;
    u.f = v;
    u.i = __builtin_amdgcn_update_dpp(0, u.i, 0xB1, 0xF, 0xF, true);
    return u.f;
}

__global__ void __launch_bounds__(64)
__attribute__((amdgpu_waves_per_eu(1, 1)))
matchnet_kernel(
    const float* __restrict__ X,
    const float* __restrict__ W1, const float* __restrict__ b1,
    const float* __restrict__ W2, const float* __restrict__ b2,
    const float* __restrict__ W3, const float* __restrict__ b3,
    const float* __restrict__ W4, const float* __restrict__ b4,
    float* __restrict__ out, int B)
{
    // Transposed weights: tW1[j*8+i] (i<6, pad 8), tW2/tW3[j*20+i], tW4[k*20+i]
    __shared__ alignas(16) float tW1[160], tW2[400], tW3[400], tW4[160];
    __shared__ alignas(16) float sb1[20], sb2[20], sb3[20], sb4[8];
    {
        int tid = threadIdx.x;
        for (int idx = tid; idx < 120; idx += 64) { int i = idx / 20, j = idx % 20; tW1[j * 8 + i] = W1[idx]; }
        for (int idx = tid; idx < 400; idx += 64) { int i = idx / 20, j = idx % 20; tW2[j * 20 + i] = W2[idx]; }
        for (int idx = tid; idx < 400; idx += 64) { int i = idx / 20, j = idx % 20; tW3[j * 20 + i] = W3[idx]; }
        for (int idx = tid; idx < 160; idx += 64) { int i = idx / 8,  k = idx % 8;  tW4[k * 20 + i] = W4[idx]; }
        if (tid < 20) { sb1[tid] = b1[tid]; sb2[tid] = b2[tid]; sb3[tid] = b3[tid]; }
        if (tid < 8) sb4[tid] = b4[tid];
    }
    __syncthreads();

    int gidx = blockIdx.x * blockDim.x + threadIdx.x;
    int row = gidx >> 1;
    if (row >= B) return;
    const bool isOdd = (gidx & 1) != 0;
    const int jb = isOdd ? 10 : 0;   // this lane's neuron range (layers 1-3)
    const int kb = isOdd ? 4 : 0;    // this lane's output range (layer 4)

    float bb0 = X[row * 6 + 0], bb1 = X[row * 6 + 1], bb2 = X[row * 6 + 2];
    float bb3 = X[row * 6 + 3], bb4 = X[row * 6 + 4], bb5 = X[row * 6 + 5];

    // --- MLP, neuron-split across the lane pair ---
    float hA[10], hB[10];   // absolute h[0..9], h[10..19] (both lanes)
    {
        // L1: 10 neurons, inputs bb0..bb5 (full in both lanes) -> bit-exact
        float acc[10];
        const f2* bv = (const f2*)&sb1[jb];
        #pragma unroll
        for (int p = 0; p < 5; p++) { f2 b = bv[p]; acc[2 * p] = b.x; acc[2 * p + 1] = b.y; }
        #pragma unroll
        for (int n = 0; n < 10; n++) {
            int j = jb + n;
            f4 w0 = *(const f4*)&tW1[j * 8];
            f2 w1 = *(const f2*)&tW1[j * 8 + 4];
            float a = acc[n];
            a = fmaf(bb0, w0.x, a); a = fmaf(bb1, w0.y, a); a = fmaf(bb2, w0.z, a);
            a = fmaf(bb3, w0.w, a); a = fmaf(bb4, w1.x, a); a = fmaf(bb5, w1.y, a);
            acc[n] = fast_tanh(a);
        }
        #pragma unroll
        for (int n = 0; n < 10; n++) {
            float t = dpp_swap(acc[n]);
            hA[n] = isOdd ? t : acc[n];
            hB[n] = isOdd ? acc[n] : t;
        }
    }
    #pragma unroll
    for (int layer = 0; layer < 2; layer++) {
        const float* tw = layer ? tW3 : tW2;
        const float* sb = layer ? sb3 : sb2;
        float acc[10];
        const f2* bv = (const f2*)&sb[jb];
        #pragma unroll
        for (int p = 0; p < 5; p++) { f2 b = bv[p]; acc[2 * p] = b.x; acc[2 * p + 1] = b.y; }
        #pragma unroll
        for (int n = 0; n < 10; n++) {
            int j = jb + n;
            const f4* w = (const f4*)&tw[j * 20];
            f4 w0 = w[0], w1 = w[1], w2 = w[2], w3 = w[3], w4 = w[4];
            float a = acc[n];
            a = fmaf(hA[0], w0.x, a); a = fmaf(hA[1], w0.y, a);
            a = fmaf(hA[2], w0.z, a); a = fmaf(hA[3], w0.w, a);
            a = fmaf(hA[4], w1.x, a); a = fmaf(hA[5], w1.y, a);
            a = fmaf(hA[6], w1.z, a); a = fmaf(hA[7], w1.w, a);
            a = fmaf(hA[8], w2.x, a); a = fmaf(hA[9], w2.y, a);
            a = fmaf(hB[0], w2.z, a); a = fmaf(hB[1], w2.w, a);
            a = fmaf(hB[2], w3.x, a); a = fmaf(hB[3], w3.y, a);
            a = fmaf(hB[4], w3.z, a); a = fmaf(hB[5], w3.w, a);
            a = fmaf(hB[6], w4.x, a); a = fmaf(hB[7], w4.y, a);
            a = fmaf(hB[8], w4.z, a); a = fmaf(hB[9], w4.w, a);
            acc[n] = fast_tanh(a);
        }
        #pragma unroll
        for (int n = 0; n < 10; n++) {
            float t = dpp_swap(acc[n]);
            hA[n] = isOdd ? t : acc[n];
            hB[n] = isOdd ? acc[n] : t;
        }
    }
    // L4: this lane's 4 outputs == exactly its z components (no exchange)
    float oz0, oz1, oz2, oz3;
    {
        f4 b = *(const f4*)&sb4[kb];
        float acc[4] = {b.x, b.y, b.z, b.w};
        #pragma unroll
        for (int n = 0; n < 4; n++) {
            int k = kb + n;
            const f4* w = (const f4*)&tW4[k * 20];
            f4 w0 = w[0], w1 = w[1], w2 = w[2], w3 = w[3], w4 = w[4];
            float a = acc[n];
            a = fmaf(hA[0], w0.x, a); a = fmaf(hA[1], w0.y, a);
            a = fmaf(hA[2], w0.z, a); a = fmaf(hA[3], w0.w, a);
            a = fmaf(hA[4], w1.x, a); a = fmaf(hA[5], w1.y, a);
            a = fmaf(hA[6], w1.z, a); a = fmaf(hA[7], w1.w, a);
            a = fmaf(hA[8], w2.x, a); a = fmaf(hA[9], w2.y, a);
            a = fmaf(hB[0], w2.z, a); a = fmaf(hB[1], w2.w, a);
            a = fmaf(hB[2], w3.x, a); a = fmaf(hB[3], w3.y, a);
            a = fmaf(hB[4], w3.z, a); a = fmaf(hB[5], w3.w, a);
            a = fmaf(hB[6], w4.x, a); a = fmaf(hB[7], w4.y, a);
            a = fmaf(hB[8], w4.z, a); a = fmaf(hB[9], w4.w, a);
            acc[n] = a;
        }
        oz0 = acc[0]; oz1 = acc[1]; oz2 = acc[2]; oz3 = acc[3];
    }

    // --- constants ---
    const float tau  = 0.18898223650461363f;   // 1/sqrt(28)
    const float c    = 0.03571428571428571f;   // tau*sigma = 1/28
    const float tauC = 1.8898223650461363f;    // tau * control_strength(10)

    float ot0 = tau - oz0, ot1 = tau - oz1, ot2 = tau - oz2, ot3 = tau - oz3;
    float oTI0 = ot0, oTI1 = ot1, oTI2 = ot2, oTI3 = ot3;

    float ox0 = fmaxf(oz0, 0.f), ox1 = fmaxf(oz1, 0.f);
    float ox2 = fmaxf(oz2, 0.f), ox3 = fmaxf(oz3, 0.f);
    float oxb0 = ox0, oxb1 = ox1, oxb2 = ox2, oxb3 = ox3;

    // dual-row constants: even rows (0,2,1) -> (cb0,cb2,cb1); odd (4,3,5)
    float cb0 = c * bb0, cb1 = c * bb1, cb2 = c * bb2;
    float cb3 = c * bb3, cb4 = c * bb4, cb5 = c * bb5;
    float cbq0 = isOdd ? cb4 : cb0;
    float cbq1 = isOdd ? cb3 : cb2;
    float cbq2 = isOdd ? cb5 : cb1;
    float Yq0 = 0.f, Yq1 = 0.f, Yq2 = 0.f;

    #pragma unroll 1
    for (int it = 0; it < N_ITERS; it++) {
        // xb exchange (4): rxb_i = partner's oxb_i
        float rxb0 = dpp_swap(oxb0), rxb1 = dpp_swap(oxb1);
        float rxb2 = dpp_swap(oxb2), rxb3 = dpp_swap(oxb3);

        // s-sums (12): even (s0,s2,s1), odd (s4,s3,s5)
        float op_a = oxb0 + rxb1;            // e: xb0+xb5 | o: xb4+xb1
        float op_b = oxb2 + rxb3;            // e: xb2+xb7 | o: garbage
        float op_c = oxb3 + rxb2;            // e: garbage | o: xb7+xb2
        float op_d = isOdd ? op_c : op_b;
        float sq0  = op_a + op_d;            // e: s0 | o: s4
        float op_e = oxb1 + rxb2;            // e: xb1+xb6 | o: xb5+xb2
        float op_f = isOdd ? rxb3 : oxb0;    // e: xb0 | o: xb3
        float sq1  = op_e + op_f;            // e: s2 | o: s3
        float op_g = oxb1 + oxb3;            // e: xb1+xb3
        float op_h = oxb0 + oxb2;            //            o: xb4+xb6
        float op_i = isOdd ? op_h : op_g;
        float sq2  = op_i + rxb0;            // e: s1 | o: s5

        // Y updates (9): Y = max(0, fma(c,s,Y) - cb)
        Yq0 = fmaxf(0.f, fmaf(c, sq0, Yq0) - cbq0);
        Yq1 = fmaxf(0.f, fmaf(c, sq1, Yq1) - cbq1);
        Yq2 = fmaxf(0.f, fmaf(c, sq2, Yq2) - cbq2);

        // Y exchange (3): e gets (Y4,Y3,Y5); o gets (Y0,Y2,Y1)
        float rY0 = dpp_swap(Yq0), rY1 = dpp_swap(Yq1), rY2 = dpp_swap(Yq2);

        // column sums (11): even cols 0-3, odd cols 4-7
        float op_j = Yq0 + rY2;              // e: Y0+Y5 | o: Y4+Y1
        float op_k = isOdd ? Yq2 : Yq1;      // e: Y2    | o: Y5
        float colq0 = op_j + op_k;           // e: col0  | o: col4
        float op_l = Yq1 + rY0;              // e: Y2+Y4 | o: Y3+Y0
        float op_p = isOdd ? 0.f : Yq2;      // e: Y1    | o: 0
        float colq1 = op_l + op_p;           // e: col1  | o: col5
        float op_m = Yq0 + rY0;              // e: Y0+Y4 | o: Y4+Y0 (=col7)
        float op_n = rY1 + Yq2;              // e: Y3+Y1 (=col3) | o: Y2+Y5 (=col6)
        float op_o = op_m + rY1;             // e: Y0+Y4+Y3 (=col2) | o: garbage
        float colq2 = isOdd ? op_n : op_o;   // e: col2 | o: col6
        float colq3 = isOdd ? op_m : op_n;   // e: col3 | o: col7

        // TI (8): TI = max(t, fma(-c, xb, TI))
        oTI0 = fmaxf(ot0, fmaf(-c, oxb0, oTI0));
        oTI1 = fmaxf(ot1, fmaf(-c, oxb1, oTI1));
        oTI2 = fmaxf(ot2, fmaf(-c, oxb2, oTI2));
        oTI3 = fmaxf(ot3, fmaf(-c, oxb3, oTI3));

        // d = (x + TI) - col  (8)
        float od0 = (ox0 + oTI0) - colq0;
        float od1 = (ox1 + oTI1) - colq1;
        float od2 = (ox2 + oTI2) - colq2;
        float od3 = (ox3 + oTI3) - colq3;

        // nsq (6): local 4-term + cross-lane add (commutative => identical)
        float nl = od0 * od0;
        nl = fmaf(od1, od1, nl);
        nl = fmaf(od2, od2, nl);
        nl = fmaf(od3, od3, nl);
        float rn = dpp_swap(nl);
        float nsq = nl + rn;

        // scale (3): max(0, 1 - tauC*rsq(nsq)); rsq(0)=inf -> 0 == ref clamp
        float rs = __builtin_amdgcn_rsqf(nsq);
        float scale = fmaxf(0.f, fmaf(-tauC, rs, 1.f));

        // xn + xb commit (8)
        float xn0 = fmaf(scale, od0, oz0);
        float xn1 = fmaf(scale, od1, oz1);
        float xn2 = fmaf(scale, od2, oz2);
        float xn3 = fmaf(scale, od3, oz3);
        oxb0 = fmaf(2.f, xn0, -ox0); ox0 = xn0;
        oxb1 = fmaf(2.f, xn1, -ox1); ox1 = xn1;
        oxb2 = fmaf(2.f, xn2, -ox2); ox2 = xn2;
        oxb3 = fmaf(2.f, xn3, -ox3); ox3 = xn3;
    }

    // even lane: comps 0-3 at out4[row*2]; odd: comps 4-7 at out4[row*2+1]
    float4* out4 = (float4*)out;
    out4[gidx] = make_float4(ox0, ox1, ox2, ox3);
}

extern "C" void kernel_launch(void* const* d_in, const int* in_sizes, int n_in,
                              void* d_out, int out_size, void* d_ws, size_t ws_size,
                              hipStream_t stream) {
    const float* X  = (const float*)d_in[0];
    const float* W1 = (const float*)d_in[1];
    const float* b1 = (const float*)d_in[2];
    const float* W2 = (const float*)d_in[3];
    const float* b2 = (const float*)d_in[4];
    const float* W3 = (const float*)d_in[5];
    const float* b3 = (const float*)d_in[6];
    const float* W4 = (const float*)d_in[7];
    const float* b4 = (const float*)d_in[8];
    float* out = (float*)d_out;

    int B = in_sizes[0] / 6;
    const int block = 64;
    long long threads = (long long)B * 2;
    int grid = (int)((threads + block - 1) / block);
    hipLaunchKernelGGL(matchnet_kernel, dim3(grid), dim3(block), 0, stream,
                       X, W1, b1, W2, b2, W3, b3, W4, b4, out, B);
}